// Round 1
// baseline (240.626 us; speedup 1.0000x reference)
//
#include <hip/hip_runtime.h>
#include <hip/hip_bf16.h>

#define B_ 8
#define H_ 56
#define W_ 56
#define C_ 384
#define HEADS_ 12
#define NPIX (B_*H_*W_)      // 25088
#define NPAD 1408            // 1356 padded to 11*128
#define KDIM 384

typedef unsigned short u16;
typedef __attribute__((ext_vector_type(4))) float f32x4;
typedef __attribute__((ext_vector_type(8))) short bf16x8;

// ---------------- pack: fp32 -> bf16 (x, [Wv;Wa;0], Wo) ----------------
__global__ void pack_kernel(const float* __restrict__ x, const float* __restrict__ Wv,
                            const float* __restrict__ Wa, const float* __restrict__ Wo,
                            __hip_bfloat16* __restrict__ xb, __hip_bfloat16* __restrict__ wcat,
                            __hip_bfloat16* __restrict__ wob) {
    const int NX = NPIX * C_;        // 9633792
    const int NW = NPAD * KDIM;      // 540672
    const int NO = C_ * C_;          // 147456
    const int total = NX + NW + NO;
    for (int idx = blockIdx.x * blockDim.x + threadIdx.x; idx < total;
         idx += gridDim.x * blockDim.x) {
        if (idx < NX) {
            xb[idx] = __float2bfloat16(x[idx]);
        } else if (idx < NX + NW) {
            int t = idx - NX;
            int o = t / KDIM;
            float v = 0.f;
            if (o < 384) v = Wv[t];
            else if (o < 1356) v = Wa[t - 147456];
            wcat[t] = __float2bfloat16(v);
        } else {
            int t = idx - NX - NW;
            wob[t] = __float2bfloat16(Wo[t]);
        }
    }
}

// ---------------- bf16 MFMA GEMM: C[M,N] = A[M,K] * B[N,K]^T ----------------
// 128x128 tile, BK=32, 256 threads (4 waves, 2x2), each wave 64x64 (4x4 frags)
template<int OUT_BF16>
__global__ __launch_bounds__(256) void gemm_bt(const u16* __restrict__ A, const u16* __restrict__ Bw,
                                               void* __restrict__ Cout, int M, int N, int K) {
    __shared__ u16 As[128 * 32];
    __shared__ u16 Bs[128 * 32];
    const int tid = threadIdx.x;
    const int bm = blockIdx.y, bn = blockIdx.x;
    const int lane = tid & 63, wid = tid >> 6;
    const int wm = wid >> 1, wn = wid & 1;
    const int fr = lane & 15;    // fragment row/col within 16
    const int kg = lane >> 4;    // k-group 0..3 (8 contiguous k each)
    f32x4 acc[4][4] = {};
    const int e0 = tid * 8;
    for (int kt = 0; kt < K; kt += 32) {
        // stage 128x32 A and B tiles: 4096 u16 each; 2 passes x 256 thr x 8 elem
#pragma unroll
        for (int pass = 0; pass < 2; ++pass) {
            int e = e0 + pass * 2048;
            int row = e >> 5, col = e & 31;
            *(int4*)(&As[e]) = *(const int4*)(&A[(size_t)(bm * 128 + row) * K + kt + col]);
            *(int4*)(&Bs[e]) = *(const int4*)(&Bw[(size_t)(bn * 128 + row) * K + kt + col]);
        }
        __syncthreads();
        bf16x8 af[4], bfr[4];
#pragma unroll
        for (int m = 0; m < 4; ++m)
            af[m] = *(const bf16x8*)(&As[(wm * 64 + m * 16 + fr) * 32 + kg * 8]);
#pragma unroll
        for (int n = 0; n < 4; ++n)
            bfr[n] = *(const bf16x8*)(&Bs[(wn * 64 + n * 16 + fr) * 32 + kg * 8]);
#pragma unroll
        for (int m = 0; m < 4; ++m)
#pragma unroll
            for (int n = 0; n < 4; ++n)
                acc[m][n] = __builtin_amdgcn_mfma_f32_16x16x32_bf16(af[m], bfr[n], acc[m][n], 0, 0, 0);
        __syncthreads();
    }
    // C/D layout: col = lane&15, row = (lane>>4)*4 + j  [verified m89/m91]
    const int r0 = bm * 128 + wm * 64 + kg * 4;
    const int c0 = bn * 128 + wn * 64 + fr;
#pragma unroll
    for (int m = 0; m < 4; ++m)
#pragma unroll
        for (int n = 0; n < 4; ++n)
#pragma unroll
            for (int j = 0; j < 4; ++j) {
                size_t off = (size_t)(r0 + m * 16 + j) * N + (c0 + n * 16);
                if (OUT_BF16) ((__hip_bfloat16*)Cout)[off] = __float2bfloat16(acc[m][n][j]);
                else          ((float*)Cout)[off] = acc[m][n][j];
            }
}

// ---------------- fused softmax + unfold*attn + fold ----------------
// One block per output pixel (b,r,s). y[r,s,c] = sum_{dy,dx} W25[dy,dx,head(c)] * v[r+dy,s+dx,c]
// W25[dy,dx,h] = sum_{i,j: center valid, qi=i+dy in [0,3), qj=j+dx in [0,3)}
//                softmax(a[center(i,j), h, p=i*3+j, :])[qi*3+qj]
__global__ __launch_bounds__(384) void attn_fold(const __hip_bfloat16* __restrict__ va,
                                                 __hip_bfloat16* __restrict__ yb) {
    const int pix = blockIdx.x;
    const int b = pix / (H_ * W_);
    const int rs = pix % (H_ * W_);
    const int r = rs / W_, s = rs % W_;
    const int tid = threadIdx.x;
    __shared__ float attn_s[9][12][9];
    __shared__ float w25[5][5][12];
    const float SC = 0.17677669529663687f;  // 1/sqrt(32)

    if (tid < 108) {  // one softmax row per (center ij, head)
        int ij = tid / 12, hh = tid % 12;
        int i = ij / 3, j = ij % 3;
        int cy = r + 1 - i, cx = s + 1 - j;
        if ((unsigned)cy < (unsigned)H_ && (unsigned)cx < (unsigned)W_) {
            const __hip_bfloat16* ap =
                va + (size_t)(b * H_ * W_ + cy * W_ + cx) * NPAD + C_ + hh * 81 + ij * 9;
            float aq[9];
            float mx = -1e30f;
#pragma unroll
            for (int q = 0; q < 9; ++q) { aq[q] = __bfloat162float(ap[q]); mx = fmaxf(mx, aq[q]); }
            float ssum = 0.f;
#pragma unroll
            for (int q = 0; q < 9; ++q) { aq[q] = __expf((aq[q] - mx) * SC); ssum += aq[q]; }
            float inv = 1.f / ssum;
#pragma unroll
            for (int q = 0; q < 9; ++q) attn_s[ij][hh][q] = aq[q] * inv;
        } else {
#pragma unroll
            for (int q = 0; q < 9; ++q) attn_s[ij][hh][q] = 0.f;
        }
    }
    __syncthreads();
    if (tid < 300) {  // collapse 81 attn terms -> 25 taps per head
        int t25 = tid / 12, hh = tid % 12;
        int dy = t25 / 5 - 2, dx = t25 % 5 - 2;
        int qi0 = dy > 0 ? dy : 0, qi1 = 3 + (dy < 0 ? dy : 0);
        int qj0 = dx > 0 ? dx : 0, qj1 = 3 + (dx < 0 ? dx : 0);
        float sum = 0.f;
        for (int qi = qi0; qi < qi1; ++qi)
            for (int qj = qj0; qj < qj1; ++qj) {
                int i = qi - dy, j = qj - dx;
                sum += attn_s[i * 3 + j][hh][qi * 3 + qj];
            }
        w25[t25 / 5][t25 % 5][hh] = sum;
    }
    __syncthreads();
    {  // 25-tap weighted gather, one channel per thread
        int c = tid, hh = c >> 5;
        float acc = 0.f;
#pragma unroll
        for (int dy = -2; dy <= 2; ++dy) {
            int py = r + dy;
            if ((unsigned)py >= (unsigned)H_) continue;
#pragma unroll
            for (int dx = -2; dx <= 2; ++dx) {
                int px = s + dx;
                if ((unsigned)px >= (unsigned)W_) continue;
                float w = w25[dy + 2][dx + 2][hh];
                acc += w * __bfloat162float(va[(size_t)(b * H_ * W_ + py * W_ + px) * NPAD + c]);
            }
        }
        yb[(size_t)pix * C_ + c] = __float2bfloat16(acc);
    }
}

// ---------------- launch ----------------
extern "C" void kernel_launch(void* const* d_in, const int* in_sizes, int n_in,
                              void* d_out, int out_size, void* d_ws, size_t ws_size,
                              hipStream_t stream) {
    const float* x  = (const float*)d_in[0];
    const float* Wv = (const float*)d_in[1];
    const float* Wa = (const float*)d_in[2];
    const float* Wo = (const float*)d_in[3];
    char* ws = (char*)d_ws;
    // ws layout (bytes):
    //   xb   @ 0          : 25088*384*2  = 19267584
    //   wcat @ 19267584   : 1408*384*2   = 1081344
    //   wob  @ 20348928   : 384*384*2    = 294912
    //   va   @ 20643840   : 25088*1408*2 = 70647808
    //   yb   @ 91291648   : 25088*384*2  = 19267584   (end: 110559232)
    __hip_bfloat16* xb   = (__hip_bfloat16*)(ws);
    __hip_bfloat16* wcat = (__hip_bfloat16*)(ws + 19267584);
    __hip_bfloat16* wob  = (__hip_bfloat16*)(ws + 20348928);
    __hip_bfloat16* va   = (__hip_bfloat16*)(ws + 20643840);
    __hip_bfloat16* yb   = (__hip_bfloat16*)(ws + 91291648);

    hipLaunchKernelGGL(pack_kernel, dim3(2048), dim3(256), 0, stream,
                       x, Wv, Wa, Wo, xb, wcat, wob);
    hipLaunchKernelGGL(HIP_KERNEL_NAME(gemm_bt<1>), dim3(NPAD / 128, NPIX / 128), dim3(256), 0,
                       stream, (const u16*)xb, (const u16*)wcat, (void*)va, NPIX, NPAD, KDIM);
    hipLaunchKernelGGL(attn_fold, dim3(NPIX), dim3(384), 0, stream, va, yb);
    hipLaunchKernelGGL(HIP_KERNEL_NAME(gemm_bt<0>), dim3(C_ / 128, NPIX / 128), dim3(256), 0,
                       stream, (const u16*)yb, (const u16*)wob, d_out, NPIX, C_, KDIM);
}

// Round 2
// 163.333 us; speedup vs baseline: 1.4732x; 1.4732x over previous
//
#include <hip/hip_runtime.h>
#include <hip/hip_bf16.h>

#define B_ 8
#define H_ 56
#define W_ 56
#define C_ 384
#define HEADS_ 12
#define NPIX (B_*H_*W_)      // 25088
#define NPAD 1408            // 1356 padded to 11*128
#define KDIM 384

typedef unsigned short u16;
typedef __attribute__((ext_vector_type(4))) float f32x4;
typedef __attribute__((ext_vector_type(8))) short bf16x8;
typedef __attribute__((ext_vector_type(8))) unsigned short u16x8;

#define GLDS16(g, l)                                                            \
    __builtin_amdgcn_global_load_lds(                                           \
        (const __attribute__((address_space(1))) void*)(g),                     \
        (__attribute__((address_space(3))) void*)(l), 16, 0, 0)

__device__ __forceinline__ float bf2f(u16 u) {
    union { unsigned int uu; float f; } cv; cv.uu = ((unsigned)u) << 16; return cv.f;
}
__device__ __forceinline__ u16 f2bf(float f) {
    __hip_bfloat16 hb = __float2bfloat16(f);
    return *reinterpret_cast<u16*>(&hb);
}

// ---------------- pack: fp32 -> bf16 (x, [Wv;Wa;0], Wo) ----------------
__global__ void pack_kernel(const float* __restrict__ x, const float* __restrict__ Wv,
                            const float* __restrict__ Wa, const float* __restrict__ Wo,
                            __hip_bfloat16* __restrict__ xb, __hip_bfloat16* __restrict__ wcat,
                            __hip_bfloat16* __restrict__ wob) {
    const int NX = NPIX * C_;        // 9633792
    const int NW = NPAD * KDIM;      // 540672
    const int NO = C_ * C_;          // 147456
    const int total = NX + NW + NO;
    for (int idx = blockIdx.x * blockDim.x + threadIdx.x; idx < total;
         idx += gridDim.x * blockDim.x) {
        if (idx < NX) {
            xb[idx] = __float2bfloat16(x[idx]);
        } else if (idx < NX + NW) {
            int t = idx - NX;
            int o = t / KDIM;
            float v = 0.f;
            if (o < 384) v = Wv[t];
            else if (o < 1356) v = Wa[t - 147456];
            wcat[t] = __float2bfloat16(v);
        } else {
            int t = idx - NX - NW;
            wob[t] = __float2bfloat16(Wo[t]);
        }
    }
}

// ---------------- bf16 MFMA GEMM: C[M,N] = A[M,K] * B[N,K]^T ----------------
// 128x128 tile, BK=32, 256 threads (4 waves, 2x2), global_load_lds width-16 staging
template<int OUT_BF16>
__global__ __launch_bounds__(256) void gemm_bt(const u16* __restrict__ A, const u16* __restrict__ Bw,
                                               void* __restrict__ Cout, int M, int N, int K) {
    __shared__ u16 As[128 * 32];
    __shared__ u16 Bs[128 * 32];
    const int tid = threadIdx.x;
    const int bm = blockIdx.y, bn = blockIdx.x;
    const int lane = tid & 63, wid = tid >> 6;
    const int wm = wid >> 1, wn = wid & 1;
    const int fr = lane & 15;    // fragment row/col within 16
    const int kg = lane >> 4;    // k-group 0..3 (8 contiguous k each)
    const int qrow = lane >> 2;      // 0..15: row within 16-row stripe
    const int qcol = (lane & 3) * 8; // 0,8,16,24: col element
    f32x4 acc[4][4] = {};
    for (int kt = 0; kt < K; kt += 32) {
        // stage 128x32 A/B tiles via async global->LDS (wave-uniform LDS base + lane*16B)
#pragma unroll
        for (int q = 0; q < 2; ++q) {
            int row = wid * 32 + q * 16 + qrow;
            GLDS16(&A[(size_t)(bm * 128 + row) * K + kt + qcol], &As[wid * 1024 + q * 512]);
            GLDS16(&Bw[(size_t)(bn * 128 + row) * K + kt + qcol], &Bs[wid * 1024 + q * 512]);
        }
        __syncthreads();
        bf16x8 af[4], bfr[4];
#pragma unroll
        for (int m = 0; m < 4; ++m)
            af[m] = *(const bf16x8*)(&As[(wm * 64 + m * 16 + fr) * 32 + kg * 8]);
#pragma unroll
        for (int n = 0; n < 4; ++n)
            bfr[n] = *(const bf16x8*)(&Bs[(wn * 64 + n * 16 + fr) * 32 + kg * 8]);
#pragma unroll
        for (int m = 0; m < 4; ++m)
#pragma unroll
            for (int n = 0; n < 4; ++n)
                acc[m][n] = __builtin_amdgcn_mfma_f32_16x16x32_bf16(af[m], bfr[n], acc[m][n], 0, 0, 0);
        __syncthreads();
    }
    // C/D layout: col = lane&15, row = (lane>>4)*4 + j  [verified m89/m91]
    const int r0 = bm * 128 + wm * 64 + kg * 4;
    const int c0 = bn * 128 + wn * 64 + fr;
#pragma unroll
    for (int m = 0; m < 4; ++m)
#pragma unroll
        for (int n = 0; n < 4; ++n)
#pragma unroll
            for (int j = 0; j < 4; ++j) {
                size_t off = (size_t)(r0 + m * 16 + j) * N + (c0 + n * 16);
                if (OUT_BF16) ((__hip_bfloat16*)Cout)[off] = __float2bfloat16(acc[m][n][j]);
                else          ((float*)Cout)[off] = acc[m][n][j];
            }
}

// ---------------- fused softmax + collapse to 25 taps ----------------
// One thread per (pixel, head). Each attn row (center,h,p) belongs to exactly one
// output pixel, so zero recompute. Statically-indexed 25-tap register accumulator.
__global__ __launch_bounds__(256) void attn_w25(const __hip_bfloat16* __restrict__ va,
                                                u16* __restrict__ w25b) {
    int idx = blockIdx.x * 256 + threadIdx.x;
    if (idx >= NPIX * HEADS_) return;
    int pix = idx / 12, h = idx - pix * 12;
    int b = pix / 3136, rs = pix - b * 3136;
    int r = rs / 56, s = rs - r * 56;
    const u16* vap = (const u16*)va;
    float w[25];
#pragma unroll
    for (int t = 0; t < 25; ++t) w[t] = 0.f;
    const float SC = 0.17677669529663687f;  // 1/sqrt(32)
#pragma unroll
    for (int i = 0; i < 3; ++i) {
        int cy = r + 1 - i;
        if ((unsigned)cy >= (unsigned)H_) continue;
#pragma unroll
        for (int j = 0; j < 3; ++j) {
            int cx = s + 1 - j;
            if ((unsigned)cx >= (unsigned)W_) continue;
            const u16* ap = vap + (size_t)(b * 3136 + cy * 56 + cx) * NPAD + C_ + h * 81 + (i * 3 + j) * 9;
            float aq[9];
            float mx = -1e30f;
#pragma unroll
            for (int q = 0; q < 9; ++q) { aq[q] = bf2f(ap[q]); mx = fmaxf(mx, aq[q]); }
            float ssum = 0.f;
#pragma unroll
            for (int q = 0; q < 9; ++q) { aq[q] = __expf((aq[q] - mx) * SC); ssum += aq[q]; }
            float inv = 1.f / ssum;
#pragma unroll
            for (int qi = 0; qi < 3; ++qi)
#pragma unroll
                for (int qj = 0; qj < 3; ++qj)
                    w[(qi - i + 2) * 5 + (qj - j + 2)] += aq[qi * 3 + qj] * inv;
        }
    }
    u16* wp = w25b + (size_t)pix * 300 + h;
#pragma unroll
    for (int t = 0; t < 25; ++t) wp[t * 12] = f2bf(w[t]);
}

// ---------------- fold: y[pix][c] = sum_taps w25[tap][head(c)] * v[tap_pixel][c] ----------------
// 8 pixels/block, 48 threads/pixel, 8 channels/thread (16B vector loads)
__global__ __launch_bounds__(384) void fold_gather(const __hip_bfloat16* __restrict__ va,
                                                   const u16* __restrict__ w25b,
                                                   __hip_bfloat16* __restrict__ yb) {
    __shared__ float wls[8][300];
    const int tid = threadIdx.x;
    const int pix0 = blockIdx.x * 8;
    for (int i = tid; i < 2400; i += 384)
        wls[i / 300][i % 300] = bf2f(w25b[(size_t)pix0 * 300 + i]);
    __syncthreads();
    const int g = tid / 48, t = tid - g * 48;
    const int c0 = t * 8, hh = t >> 2;
    const int pix = pix0 + g;
    const int b = pix / 3136, rs = pix - b * 3136;
    const int r = rs / 56, s = rs - r * 56;
    const u16* vap = (const u16*)va;
    float acc[8];
#pragma unroll
    for (int e = 0; e < 8; ++e) acc[e] = 0.f;
    const float* wp = &wls[g][hh];
#pragma unroll
    for (int dy = -2; dy <= 2; ++dy) {
        int py = r + dy;
        if ((unsigned)py >= (unsigned)H_) continue;
#pragma unroll
        for (int dx = -2; dx <= 2; ++dx) {
            int px = s + dx;
            if ((unsigned)px >= (unsigned)W_) continue;
            float w = wp[((dy + 2) * 5 + (dx + 2)) * 12];
            u16x8 v = *(const u16x8*)(vap + (size_t)(b * 3136 + py * 56 + px) * NPAD + c0);
#pragma unroll
            for (int e = 0; e < 8; ++e) acc[e] += w * bf2f(v[e]);
        }
    }
    u16x8 o;
#pragma unroll
    for (int e = 0; e < 8; ++e) o[e] = f2bf(acc[e]);
    *(u16x8*)((u16*)yb + (size_t)pix * C_ + c0) = o;
}

// ---------------- launch ----------------
extern "C" void kernel_launch(void* const* d_in, const int* in_sizes, int n_in,
                              void* d_out, int out_size, void* d_ws, size_t ws_size,
                              hipStream_t stream) {
    const float* x  = (const float*)d_in[0];
    const float* Wv = (const float*)d_in[1];
    const float* Wa = (const float*)d_in[2];
    const float* Wo = (const float*)d_in[3];
    char* ws = (char*)d_ws;
    // ws layout (bytes):
    //   xb   @ 0          : 25088*384*2  = 19267584   (dead after gemm1)
    //   W25b @ 0          : 25088*300*2  = 15052800   (reuses xb region; live after gemm1)
    //   wcat @ 19267584   : 1408*384*2   = 1081344
    //   wob  @ 20348928   : 384*384*2    = 294912
    //   va   @ 20643840   : 25088*1408*2 = 70647808
    //   yb   @ 91291648   : 25088*384*2  = 19267584   (end: 110559232)
    __hip_bfloat16* xb   = (__hip_bfloat16*)(ws);
    u16*            w25b = (u16*)(ws);
    __hip_bfloat16* wcat = (__hip_bfloat16*)(ws + 19267584);
    __hip_bfloat16* wob  = (__hip_bfloat16*)(ws + 20348928);
    __hip_bfloat16* va   = (__hip_bfloat16*)(ws + 20643840);
    __hip_bfloat16* yb   = (__hip_bfloat16*)(ws + 91291648);

    hipLaunchKernelGGL(pack_kernel, dim3(2048), dim3(256), 0, stream,
                       x, Wv, Wa, Wo, xb, wcat, wob);
    hipLaunchKernelGGL(HIP_KERNEL_NAME(gemm_bt<1>), dim3(NPAD / 128, NPIX / 128), dim3(256), 0,
                       stream, (const u16*)xb, (const u16*)wcat, (void*)va, NPIX, NPAD, KDIM);
    hipLaunchKernelGGL(attn_w25, dim3((NPIX * HEADS_ + 255) / 256), dim3(256), 0, stream,
                       va, w25b);
    hipLaunchKernelGGL(fold_gather, dim3(NPIX / 8), dim3(384), 0, stream, va, w25b, yb);
    hipLaunchKernelGGL(HIP_KERNEL_NAME(gemm_bt<0>), dim3(C_ / 128, NPIX / 128), dim3(256), 0,
                       stream, (const u16*)yb, (const u16*)wob, d_out, NPIX, C_, KDIM);
}

// Round 3
// 152.618 us; speedup vs baseline: 1.5767x; 1.0702x over previous
//
#include <hip/hip_runtime.h>
#include <hip/hip_bf16.h>

#define B_ 8
#define H_ 56
#define W_ 56
#define C_ 384
#define HEADS_ 12
#define NPIX (B_*H_*W_)      // 25088
#define NPAD 1408            // 1356 padded to 11*128
#define KDIM 384

typedef unsigned short u16;
typedef __attribute__((ext_vector_type(4))) float f32x4;
typedef __attribute__((ext_vector_type(8))) short bf16x8;
typedef __attribute__((ext_vector_type(8))) unsigned short u16x8;

#define GLDS16(g, l)                                                            \
    __builtin_amdgcn_global_load_lds(                                           \
        (const __attribute__((address_space(1))) void*)(g),                     \
        (__attribute__((address_space(3))) void*)(l), 16, 0, 0)

__device__ __forceinline__ float bf2f(u16 u) {
    union { unsigned int uu; float f; } cv; cv.uu = ((unsigned)u) << 16; return cv.f;
}
__device__ __forceinline__ u16 f2bf(float f) {
    __hip_bfloat16 hb = __float2bfloat16(f);
    return *reinterpret_cast<u16*>(&hb);
}

// ---------------- pack: fp32 -> bf16 (x vectorized, [Wv;Wa;0], Wo) ----------------
__global__ void pack_kernel(const float* __restrict__ x, const float* __restrict__ Wv,
                            const float* __restrict__ Wa, const float* __restrict__ Wo,
                            u16* __restrict__ xb, __hip_bfloat16* __restrict__ wcat,
                            __hip_bfloat16* __restrict__ wob) {
    const int NX8 = NPIX * C_ / 8;   // 1204224 (x in 8-float chunks)
    const int NW = NPAD * KDIM;      // 540672
    const int NO = C_ * C_;          // 147456
    const int total = NX8 + NW + NO;
    for (int idx = blockIdx.x * blockDim.x + threadIdx.x; idx < total;
         idx += gridDim.x * blockDim.x) {
        if (idx < NX8) {
            float4 a = ((const float4*)x)[idx * 2];
            float4 b = ((const float4*)x)[idx * 2 + 1];
            u16x8 o;
            o[0] = f2bf(a.x); o[1] = f2bf(a.y); o[2] = f2bf(a.z); o[3] = f2bf(a.w);
            o[4] = f2bf(b.x); o[5] = f2bf(b.y); o[6] = f2bf(b.z); o[7] = f2bf(b.w);
            ((u16x8*)xb)[idx] = o;
        } else if (idx < NX8 + NW) {
            int t = idx - NX8;
            int o = t / KDIM;
            float v = 0.f;
            if (o < 384) v = Wv[t];
            else if (o < 1356) v = Wa[t - 147456];
            wcat[t] = __float2bfloat16(v);
        } else {
            int t = idx - NX8 - NW;
            wob[t] = __float2bfloat16(Wo[t]);
        }
    }
}

// ---------------- bf16 MFMA GEMM: C[M,N] = A[M,K] * B[N,K]^T ----------------
// 128x128 tile, BK=64, 256 threads (4 waves, 2x2). T2 XOR-swizzled LDS via
// pre-swizzled global source (linear gload_lds dest + swizzled ds_read).
// T1 bijective XCD chunk swizzle on a 1D grid (m204).
template<int OUT_BF16>
__global__ __launch_bounds__(256) void gemm_bt(const u16* __restrict__ A, const u16* __restrict__ Bw,
                                               void* __restrict__ Cout, int N, int K,
                                               int gridN, int q, int r) {
    __shared__ u16 As[128 * 64];
    __shared__ u16 Bs[128 * 64];
    const int bid = blockIdx.x;
    const int xcd = bid & 7, ii = bid >> 3;
    const int logical = (xcd < r) ? xcd * (q + 1) + ii : r * (q + 1) + (xcd - r) * q + ii;
    const int bm = logical / gridN, bn = logical - bm * gridN;
    const int tid = threadIdx.x;
    const int lane = tid & 63, wid = tid >> 6;
    const int wm = wid >> 1, wn = wid & 1;
    const int fr = lane & 15;    // fragment row/col within 16
    const int kg = lane >> 4;    // k-group 0..3 (8 contiguous k each)
    const int srow = lane >> 3;  // staging: row-within-8 (0..7)
    const int sslot = lane & 7;  // staging: 16B slot (0..7)
    f32x4 acc[4][4] = {};
    for (int kt = 0; kt < K; kt += 64) {
        // stage 128x64 A/B tiles; lane (srow,sslot) -> linear LDS chunk, source col
        // inverse-swizzled so LDS(row,slot) holds G(row, slot^(row&7))
#pragma unroll
        for (int c = 0; c < 4; ++c) {
            int rowA = (wid * 4 + c) * 8 + srow;           // 0..127
            int scol = (sslot ^ srow) * 8;                 // (slot ^ (row&7)) * 8
            GLDS16(&A[(size_t)(bm * 128 + rowA) * K + kt + scol], &As[(wid * 4 + c) * 512]);
            GLDS16(&Bw[(size_t)(bn * 128 + rowA) * K + kt + scol], &Bs[(wid * 4 + c) * 512]);
        }
        __syncthreads();
#pragma unroll
        for (int ks = 0; ks < 2; ++ks) {
            bf16x8 af[4], bfr[4];
#pragma unroll
            for (int m = 0; m < 4; ++m) {
                int row = wm * 64 + m * 16 + fr;
                int slot = (ks * 4 + kg) ^ (row & 7);
                af[m] = *(const bf16x8*)(&As[row * 64 + slot * 8]);
            }
#pragma unroll
            for (int n = 0; n < 4; ++n) {
                int row = wn * 64 + n * 16 + fr;
                int slot = (ks * 4 + kg) ^ (row & 7);
                bfr[n] = *(const bf16x8*)(&Bs[row * 64 + slot * 8]);
            }
#pragma unroll
            for (int m = 0; m < 4; ++m)
#pragma unroll
                for (int n = 0; n < 4; ++n)
                    acc[m][n] = __builtin_amdgcn_mfma_f32_16x16x32_bf16(af[m], bfr[n], acc[m][n], 0, 0, 0);
        }
        __syncthreads();
    }
    // C/D layout: col = lane&15, row = (lane>>4)*4 + j  [verified m89/m91]
    const int r0 = bm * 128 + wm * 64 + kg * 4;
    const int c0 = bn * 128 + wn * 64 + fr;
#pragma unroll
    for (int m = 0; m < 4; ++m)
#pragma unroll
        for (int n = 0; n < 4; ++n)
#pragma unroll
            for (int j = 0; j < 4; ++j) {
                size_t off = (size_t)(r0 + m * 16 + j) * N + (c0 + n * 16);
                if (OUT_BF16) ((__hip_bfloat16*)Cout)[off] = __float2bfloat16(acc[m][n][j]);
                else          ((float*)Cout)[off] = acc[m][n][j];
            }
}

// ---------------- fused softmax + collapse to 25 taps ----------------
__global__ __launch_bounds__(256) void attn_w25(const __hip_bfloat16* __restrict__ va,
                                                u16* __restrict__ w25b) {
    int idx = blockIdx.x * 256 + threadIdx.x;
    if (idx >= NPIX * HEADS_) return;
    int pix = idx / 12, h = idx - pix * 12;
    int b = pix / 3136, rs = pix - b * 3136;
    int r = rs / 56, s = rs - r * 56;
    const u16* vap = (const u16*)va;
    float w[25];
#pragma unroll
    for (int t = 0; t < 25; ++t) w[t] = 0.f;
    const float SC = 0.17677669529663687f;  // 1/sqrt(32)
#pragma unroll
    for (int i = 0; i < 3; ++i) {
        int cy = r + 1 - i;
        if ((unsigned)cy >= (unsigned)H_) continue;
#pragma unroll
        for (int j = 0; j < 3; ++j) {
            int cx = s + 1 - j;
            if ((unsigned)cx >= (unsigned)W_) continue;
            const u16* ap = vap + (size_t)(b * 3136 + cy * 56 + cx) * NPAD + C_ + h * 81 + (i * 3 + j) * 9;
            float aq[9];
            float mx = -1e30f;
#pragma unroll
            for (int q = 0; q < 9; ++q) { aq[q] = bf2f(ap[q]); mx = fmaxf(mx, aq[q]); }
            float ssum = 0.f;
#pragma unroll
            for (int q = 0; q < 9; ++q) { aq[q] = __expf((aq[q] - mx) * SC); ssum += aq[q]; }
            float inv = 1.f / ssum;
#pragma unroll
            for (int qi = 0; qi < 3; ++qi)
#pragma unroll
                for (int qj = 0; qj < 3; ++qj)
                    w[(qi - i + 2) * 5 + (qj - j + 2)] += aq[qi * 3 + qj] * inv;
        }
    }
    u16* wp = w25b + (size_t)pix * 300 + h;
#pragma unroll
    for (int t = 0; t < 25; ++t) wp[t * 12] = f2bf(w[t]);
}

// ---------------- fold: y[pix][c] = sum_taps w25[tap][head(c)] * v[tap_pixel][c] ----------------
__global__ __launch_bounds__(384) void fold_gather(const __hip_bfloat16* __restrict__ va,
                                                   const u16* __restrict__ w25b,
                                                   __hip_bfloat16* __restrict__ yb) {
    __shared__ float wls[8][300];
    const int tid = threadIdx.x;
    const int pix0 = blockIdx.x * 8;
    for (int i = tid; i < 2400; i += 384)
        wls[i / 300][i % 300] = bf2f(w25b[(size_t)pix0 * 300 + i]);
    __syncthreads();
    const int g = tid / 48, t = tid - g * 48;
    const int c0 = t * 8, hh = t >> 2;
    const int pix = pix0 + g;
    const int b = pix / 3136, rs = pix - b * 3136;
    const int r = rs / 56, s = rs - r * 56;
    const u16* vap = (const u16*)va;
    float acc[8];
#pragma unroll
    for (int e = 0; e < 8; ++e) acc[e] = 0.f;
    const float* wp = &wls[g][hh];
#pragma unroll
    for (int dy = -2; dy <= 2; ++dy) {
        int py = r + dy;
        if ((unsigned)py >= (unsigned)H_) continue;
#pragma unroll
        for (int dx = -2; dx <= 2; ++dx) {
            int px = s + dx;
            if ((unsigned)px >= (unsigned)W_) continue;
            float w = wp[((dy + 2) * 5 + (dx + 2)) * 12];
            u16x8 v = *(const u16x8*)(vap + (size_t)(b * 3136 + py * 56 + px) * NPAD + c0);
#pragma unroll
            for (int e = 0; e < 8; ++e) acc[e] += w * bf2f(v[e]);
        }
    }
    u16x8 o;
#pragma unroll
    for (int e = 0; e < 8; ++e) o[e] = f2bf(acc[e]);
    *(u16x8*)((u16*)yb + (size_t)pix * C_ + c0) = o;
}

// ---------------- launch ----------------
extern "C" void kernel_launch(void* const* d_in, const int* in_sizes, int n_in,
                              void* d_out, int out_size, void* d_ws, size_t ws_size,
                              hipStream_t stream) {
    const float* x  = (const float*)d_in[0];
    const float* Wv = (const float*)d_in[1];
    const float* Wa = (const float*)d_in[2];
    const float* Wo = (const float*)d_in[3];
    char* ws = (char*)d_ws;
    // ws layout (bytes):
    //   xb/W25b @ 0        : 19267584 (xb dead after gemm1; w25b reuses)
    //   wcat @ 19267584    : 1081344
    //   wob  @ 20348928    : 294912
    //   va   @ 20643840    : 70647808
    //   yb   @ 91291648    : 19267584   (end: 110559232)
    u16*            xb   = (u16*)(ws);
    u16*            w25b = (u16*)(ws);
    __hip_bfloat16* wcat = (__hip_bfloat16*)(ws + 19267584);
    __hip_bfloat16* wob  = (__hip_bfloat16*)(ws + 20348928);
    __hip_bfloat16* va   = (__hip_bfloat16*)(ws + 20643840);
    __hip_bfloat16* yb   = (__hip_bfloat16*)(ws + 91291648);

    hipLaunchKernelGGL(pack_kernel, dim3(2048), dim3(256), 0, stream,
                       x, Wv, Wa, Wo, xb, wcat, wob);

    // gemm1: grid = 196 (M) x 11 (N) = 2156 blocks, XCD-chunked
    {
        int gridN = NPAD / 128, nwg = (NPIX / 128) * gridN;
        int q = nwg / 8, r = nwg % 8;
        hipLaunchKernelGGL(HIP_KERNEL_NAME(gemm_bt<1>), dim3(nwg), dim3(256), 0, stream,
                           (const u16*)xb, (const u16*)wcat, (void*)va, NPAD, KDIM, gridN, q, r);
    }
    hipLaunchKernelGGL(attn_w25, dim3((NPIX * HEADS_ + 255) / 256), dim3(256), 0, stream,
                       va, w25b);
    hipLaunchKernelGGL(fold_gather, dim3(NPIX / 8), dim3(384), 0, stream, va, w25b, yb);
    // gemm2: grid = 196 x 3 = 588 blocks
    {
        int gridN = C_ / 128, nwg = (NPIX / 128) * gridN;
        int q = nwg / 8, r = nwg % 8;
        hipLaunchKernelGGL(HIP_KERNEL_NAME(gemm_bt<0>), dim3(nwg), dim3(256), 0, stream,
                           (const u16*)yb, (const u16*)wob, d_out, C_, KDIM, gridN, q, r);
    }
}